// Round 8
// baseline (200.987 us; speedup 1.0000x reference)
//
#include <hip/hip_runtime.h>

// x [B=8, H=224, W=224, D=8, C=8] fp32, out [8, 8, 8, 10] fp32.
// Compute layout (proven r3/r6/r7): lane = w-column (55 owned + 9 halo),
// 2 channels/lane, DPP wave_shl:1 for the col+1 neighbor, loop-based phase
// guards (NEVER unroll the row phases into straight line: rounds 4/5 spilled).
// ROUND-8: distance-2 LDS pipeline. Round 7 read row h AFTER the barrier that
// published it -> ~120cy ds_read latency on the critical path every row, with
// all 4 waves of a block stalling in lockstep (barrier-synced). Now iter rel:
//   barrier; write row rel+2 -> slot[rel&1]; read row rel+1 -> cpn (latency
//   hides under row rel's ~190cy compute); load row rel+3 -> g; compute(cp);
//   cp = cpn.
// Slot invariants: row r lives in slot[r&1]; the slot written this iter held
// row rel (consumed last iter, ordered by this barrier); the slot read was
// written last iter (ordered by this barrier). One barrier per row.
#define BB 8
#define HH 224
#define WW 224
#define DCH 64
#define NS 10
#define SEG 55    // owned output columns per wave (lanes 55..63 = halo)
#define NSEG 5    // 5*55 = 275 >= 224 (last segment ragged)
#define STRIP 28  // output rows per h-strip
#define NHS 8     // 8*28 = 224
#define NCG 8     // 8 channel-groups of 8 ch per block (wave = 2 ch)
#define NBLK (BB * NCG * NSEG * NHS) // 2560 = 8 XCDs * 320 (one batch per XCD)
#define PS 72                        // LDS plane stride in floats (64 + 8 pad)
#define LDSBUF (8 * PS)              // floats per row slot (8 ch planes)

__global__ void zero_kernel(float* out, int n) {
    int i = blockIdx.x * blockDim.x + threadIdx.x;
    if (i < n) out[i] = 0.0f;
}

__global__ void finalize_kernel(float* out, int n) {
    int i = blockIdx.x * blockDim.x + threadIdx.x;
    if (i < n) out[i] = fmaxf(out[i], 0.0f) + 1.0f;
}

// lane i <- lane i+1, full-wave shift (DPP WAVE_SHL1 = 0x130). Lane 63 gets 0
// (bound_ctrl) -- only ever feeds halo/masked outputs. Verified r3/r6/r7.
__device__ __forceinline__ float dpp_shl1(float v) {
    return __int_as_float(__builtin_amdgcn_mov_dpp(__float_as_int(v), 0x130, 0xF, 0xF, true));
}

// One input row through the 2x2 max cascade (byte-identical to rounds 6/7).
// PHASE: 0 = warmup (guard r>=row0), 1 = steady, 2 = tail (guard r<row0+STRIP).
template<int PHASE>
__device__ __forceinline__ void row_body(int h, int row0, const float (&m)[NS],
                                         float (&cp)[2], float (&prev)[NS - 1][2],
                                         float (&acc)[NS][2]) {
    if (PHASE != 2) { // scale 1: raw row
        acc[0][0] = fmaf(cp[0], m[0], acc[0][0]);
        acc[0][1] = fmaf(cp[1], m[0], acc[0][1]);
    }
#pragma unroll
    for (int lv = 0; lv < NS - 1; ++lv) { // level lv -> scale lv+2, out row h-lv-1
        float vm0 = fmaxf(prev[lv][0], cp[0]); // vertical max (rows h-1, h)
        float vm1 = fmaxf(prev[lv][1], cp[1]);
        prev[lv][0] = cp[0];                   // rotate history
        prev[lv][1] = cp[1];
        cp[0] = fmaxf(vm0, dpp_shl1(vm0));     // horizontal max (cols j, j+1)
        cp[1] = fmaxf(vm1, dpp_shl1(vm1));
        bool on = true; // uniform -> s_cmp + s_cbranch
        if (PHASE == 0) on = (h - lv - 1) >= row0;
        if (PHASE == 2) on = (h - lv - 1) < row0 + STRIP;
        if (on) {
            acc[lv + 1][0] = fmaf(cp[0], m[lv + 1], acc[lv + 1][0]);
            acc[lv + 1][1] = fmaf(cp[1], m[lv + 1], acc[lv + 1][1]);
        }
    }
}

__global__ __launch_bounds__(256, 4) void pool_kernel(const float* __restrict__ x,
                                                      float* __restrict__ out) {
    __shared__ float lds[2 * LDSBUF]; // 4608 B: two row slots

    // Bijective XCD swizzle: 2560 = 8*320 -> XCD k owns batch k.
    const int phys = blockIdx.x;
    const int logical = (phys & 7) * (NBLK / 8) + (phys >> 3);
    const int b = logical / (NCG * NSEG * NHS);
    const int r = logical % (NCG * NSEG * NHS);
    const int cg = r & 7;
    const int ws = (r >> 3) % NSEG;
    const int hs = (r >> 3) / NSEG;

    const int wv   = threadIdx.x >> 6;
    const int lane = threadIdx.x & 63;
    const int ch   = cg * 8 + wv * 2;      // this wave's 2 channels
    const int col  = ws * SEG + lane;      // this lane's column (compute view)
    const int row0 = hs * STRIP;
    const int R    = min(STRIP + NS - 1, HH - row0); // 37 rows (28 bottom strip)

    float m[NS]; // per-scale column ownership (0/1, used via fma)
#pragma unroll
    for (int s = 1; s <= NS; ++s)
        m[s - 1] = (lane < SEG && col <= WW - s) ? 1.0f : 0.0f;

    float prev[NS - 1][2], acc[NS][2], cp[2], cpn[2];
#pragma unroll
    for (int lv = 0; lv < NS - 1; ++lv) { prev[lv][0] = 0.0f; prev[lv][1] = 0.0f; }
#pragma unroll
    for (int s = 0; s < NS; ++s) { acc[s][0] = 0.0f; acc[s][1] = 0.0f; }

    // Stager mapping (all 256 threads): thread t -> column t>>2, channel-pair
    // t&3 -> coalesced 8B chunks, 16 line-touches per wave, tile loaded once.
    const int scol = threadIdx.x >> 2;
    const int q    = threadIdx.x & 3;
    const int gcol = min(ws * SEG + scol, WW - 1); // right-edge clamp (masked)
    const float* sp0 = x + (((size_t)(b * HH + row0) * WW + gcol) * DCH + cg * 8 + q * 2);
    const ptrdiff_t rstride = (ptrdiff_t)WW * DCH;

    // LDS addrs: write planes 2q,2q+1 at col scol; read planes 2wv,2wv+1 at
    // col lane. PS=72 pad -> both are exactly 2-way bank accesses (free).
    const int wbase = (2 * q) * PS + scol;
    const int rbase = (2 * wv) * PS + lane;

    // Prologue: rows 0,1 -> slots 0,1; g <- row 2 (R >= 28, all valid);
    // cp <- row 0 (single exposed ds_read latency).
    { float2 t0 = *(const float2*)sp0;
      lds[wbase] = t0.x; lds[wbase + PS] = t0.y; }
    { float2 t1 = *(const float2*)(sp0 + rstride);
      lds[LDSBUF + wbase] = t1.x; lds[LDSBUF + wbase + PS] = t1.y; }
    float2 g = *(const float2*)(sp0 + 2 * rstride);
    __syncthreads();
    cp[0] = lds[rbase]; cp[1] = lds[rbase + PS];

    // Invariant at top of iter rel: cp = row rel, slot[(rel+1)&1] = row rel+1
    // (published), g = row rel+2.
#define ROW_STEP(P)                                                           \
    {                                                                         \
        __syncthreads();                                                      \
        const int wb = (rel & 1) ? LDSBUF : 0;  /* slot of row rel+2 */       \
        const int rb = LDSBUF - wb;             /* slot of row rel+1 */       \
        lds[wb + wbase] = g.x; lds[wb + wbase + PS] = g.y;                    \
        cpn[0] = lds[rb + rbase]; cpn[1] = lds[rb + rbase + PS];              \
        { const int rr = min(rel + 3, R - 1); /* uniform clamp */             \
          g = *(const float2*)(sp0 + (size_t)rr * rstride); }                 \
        row_body<P>(row0 + rel, row0, m, cp, prev, acc);                      \
        cp[0] = cpn[0]; cp[1] = cpn[1];                                       \
    }

    int rel = 0;
#pragma unroll 2
    for (; rel < NS - 1; ++rel) ROW_STEP(0)            // 9 warmup rows
    const int sEnd = min(STRIP, R);                    // 28
#pragma unroll 2
    for (; rel < sEnd; ++rel) ROW_STEP(1)              // 19 branch-free rows
#pragma unroll 2
    for (; rel < R; ++rel) ROW_STEP(2)                 // <=9 tail rows
#undef ROW_STEP

    // Wave butterfly reduction (one-time), then lane 0 atomics 20 partials.
#pragma unroll
    for (int s = 0; s < NS; ++s) {
#pragma unroll
        for (int c = 0; c < 2; ++c) {
            float v = acc[s][c];
#pragma unroll
            for (int off = 32; off > 0; off >>= 1) v += __shfl_xor(v, off);
            if (lane == 0) atomicAdd(&out[((size_t)b * DCH + ch + c) * NS + s], v);
        }
    }
}

extern "C" void kernel_launch(void* const* d_in, const int* in_sizes, int n_in,
                              void* d_out, int out_size, void* d_ws, size_t ws_size,
                              hipStream_t stream) {
    const float* x = (const float*)d_in[0];
    float* out = (float*)d_out;
    const int nblk = (out_size + 255) / 256;
    zero_kernel<<<nblk, 256, 0, stream>>>(out, out_size);
    pool_kernel<<<NBLK, 256, 0, stream>>>(x, out);
    finalize_kernel<<<nblk, 256, 0, stream>>>(out, out_size);
}

// Round 9
// 188.530 us; speedup vs baseline: 1.0661x; 1.0661x over previous
//
#include <hip/hip_runtime.h>

// x [B=8, H=224, W=224, D=8, C=8] fp32, out [8, 8, 8, 10] fp32.
// Compute layout (proven r3/r6/r7): lane = w-column (55 owned + 9 halo),
// 2 channels/lane, DPP wave_shl:1 for the col+1 neighbor, loop-based phase
// guards (NEVER straight-line the row phases: rounds 4/5 spilled).
// Load path (r7): block stages each row's 64col x 8ch tile into LDS coalesced
// (thread t -> col t>>2, chpair t&3: 16 line-touches/wave, tile loaded once),
// distance-1 LDS pipeline, one barrier/row. r8's distance-2 variant cut VALU
// 20% but stalled more (88->96us) -- reverted.
// ROUND-9: single knob on the r7 source: STRIP 28->56 (NHS 8->4). Halo rows
// per strip drop 37/28=1.32x -> 65/56=1.16x = -12% total wave-rows. r6 proved
// occupancy is not binding for this family, so the halved grid (1280 blocks)
// is free and the work cut should convert ~1:1 (we're VALU-issue-bound at
// VALUBusy 75%).
#define BB 8
#define HH 224
#define WW 224
#define DCH 64
#define NS 10
#define SEG 55    // owned output columns per wave (lanes 55..63 = halo)
#define NSEG 5    // 5*55 = 275 >= 224 (last segment ragged)
#define STRIP 56  // output rows per h-strip  (r7 had 28)
#define NHS 4     // 4*56 = 224
#define NCG 8     // 8 channel-groups of 8 ch per block (wave = 2 ch)
#define NBLK (BB * NCG * NSEG * NHS) // 1280 = 8 XCDs * 160 (one batch per XCD)
#define PS 72                        // LDS plane stride in floats (64 + 8 pad)
#define LDSBUF (8 * PS)              // floats per row buffer (8 ch planes)

__global__ void zero_kernel(float* out, int n) {
    int i = blockIdx.x * blockDim.x + threadIdx.x;
    if (i < n) out[i] = 0.0f;
}

__global__ void finalize_kernel(float* out, int n) {
    int i = blockIdx.x * blockDim.x + threadIdx.x;
    if (i < n) out[i] = fmaxf(out[i], 0.0f) + 1.0f;
}

// lane i <- lane i+1, full-wave shift (DPP WAVE_SHL1 = 0x130). Lane 63 gets 0
// (bound_ctrl) -- only ever feeds halo/masked outputs. Verified r3/r6/r7.
__device__ __forceinline__ float dpp_shl1(float v) {
    return __int_as_float(__builtin_amdgcn_mov_dpp(__float_as_int(v), 0x130, 0xF, 0xF, true));
}

// One input row through the 2x2 max cascade (byte-identical to rounds 6/7).
// PHASE: 0 = warmup (guard r>=row0), 1 = steady, 2 = tail (guard r<row0+STRIP).
template<int PHASE>
__device__ __forceinline__ void row_body(int h, int row0, const float (&m)[NS],
                                         float (&cp)[2], float (&prev)[NS - 1][2],
                                         float (&acc)[NS][2]) {
    if (PHASE != 2) { // scale 1: raw row
        acc[0][0] = fmaf(cp[0], m[0], acc[0][0]);
        acc[0][1] = fmaf(cp[1], m[0], acc[0][1]);
    }
#pragma unroll
    for (int lv = 0; lv < NS - 1; ++lv) { // level lv -> scale lv+2, out row h-lv-1
        float vm0 = fmaxf(prev[lv][0], cp[0]); // vertical max (rows h-1, h)
        float vm1 = fmaxf(prev[lv][1], cp[1]);
        prev[lv][0] = cp[0];                   // rotate history
        prev[lv][1] = cp[1];
        cp[0] = fmaxf(vm0, dpp_shl1(vm0));     // horizontal max (cols j, j+1)
        cp[1] = fmaxf(vm1, dpp_shl1(vm1));
        bool on = true; // uniform -> s_cmp + s_cbranch
        if (PHASE == 0) on = (h - lv - 1) >= row0;
        if (PHASE == 2) on = (h - lv - 1) < row0 + STRIP;
        if (on) {
            acc[lv + 1][0] = fmaf(cp[0], m[lv + 1], acc[lv + 1][0]);
            acc[lv + 1][1] = fmaf(cp[1], m[lv + 1], acc[lv + 1][1]);
        }
    }
}

__global__ __launch_bounds__(256, 4) void pool_kernel(const float* __restrict__ x,
                                                      float* __restrict__ out) {
    __shared__ float lds[2 * LDSBUF]; // 4608 B: double-buffered row tile

    // Bijective XCD swizzle: 1280 = 8*160 -> XCD k owns batch k (tile re-reads
    // across channel-group blocks and the output atomics stay in one L2).
    const int phys = blockIdx.x;
    const int logical = (phys & 7) * (NBLK / 8) + (phys >> 3);
    const int b = logical / (NCG * NSEG * NHS);
    const int r = logical % (NCG * NSEG * NHS);
    const int cg = r & 7;
    const int ws = (r >> 3) % NSEG;
    const int hs = (r >> 3) / NSEG;

    const int wv   = threadIdx.x >> 6;
    const int lane = threadIdx.x & 63;
    const int ch   = cg * 8 + wv * 2;      // this wave's 2 channels
    const int col  = ws * SEG + lane;      // this lane's column (compute view)
    const int row0 = hs * STRIP;
    const int rend = min(row0 + STRIP + NS - 1, HH); // 65 rows (56 bottom strip)

    float m[NS]; // per-scale column ownership (0/1, used via fma)
#pragma unroll
    for (int s = 1; s <= NS; ++s)
        m[s - 1] = (lane < SEG && col <= WW - s) ? 1.0f : 0.0f;

    float prev[NS - 1][2], acc[NS][2], cp[2];
#pragma unroll
    for (int lv = 0; lv < NS - 1; ++lv) { prev[lv][0] = 0.0f; prev[lv][1] = 0.0f; }
#pragma unroll
    for (int s = 0; s < NS; ++s) { acc[s][0] = 0.0f; acc[s][1] = 0.0f; }

    // ---- Stager mapping (all 256 threads): coalesced 8B chunks ----
    // thread t -> column t>>2, channel-pair t&3: wave covers 16 cols x 32B
    // slices = 16 line-touches (vs 64 for the per-lane gather).
    const int scol = threadIdx.x >> 2;
    const int q    = threadIdx.x & 3;
    const int gcol = min(ws * SEG + scol, WW - 1); // right-edge clamp (masked later)
    const float* sp = x + (((size_t)(b * HH + row0) * WW + gcol) * DCH + cg * 8 + q * 2);
    const ptrdiff_t rstride = (ptrdiff_t)WW * DCH;

    // LDS indices. Write: planes 2q, 2q+1 at col scol. Read: planes 2wv, 2wv+1
    // at col lane. PS=72 pad makes both exactly 2-way bank accesses (free).
    const int wbase = (2 * q) * PS + scol;
    const int rbase = (2 * wv) * PS + lane;

    // Prologue: row0 -> buf0; g <- row row0+1 (row0+1 < rend always).
    { float2 t0 = *(const float2*)sp;
      lds[wbase] = t0.x; lds[wbase + PS] = t0.y; }
    sp += rstride;
    float2 g = *(const float2*)sp;
    int sb = 0; // current read-buffer base (0 or LDSBUF)

    // Invariant at top of iter h: lds[sb..] = row h, g = row h+1.
    // One barrier/row: orders last iter's writes (row h into sb) before reads,
    // and last iter's reads (sb^) before this iter's writes into sb^.
#define ROW_STEP(P)                                                           \
    {                                                                         \
        __syncthreads();                                                      \
        const int so = sb ^ LDSBUF;                                           \
        lds[so + wbase] = g.x; lds[so + wbase + PS] = g.y; /* row h+1 */      \
        if (h + 2 < rend) { sp += rstride; g = *(const float2*)sp; }          \
        cp[0] = lds[sb + rbase]; cp[1] = lds[sb + rbase + PS]; /* row h */    \
        row_body<P>(h, row0, m, cp, prev, acc);                               \
        sb = so;                                                              \
    }

    int h = row0;
    const int warm_end = row0 + NS - 1;                // 9 warmup rows
    for (; h < warm_end; ++h) ROW_STEP(0)
    const int steady_end = min(row0 + STRIP, rend);    // 47 branch-free rows
    for (; h < steady_end; ++h) ROW_STEP(1)
    for (; h < rend; ++h) ROW_STEP(2)                  // <=9 tail rows
#undef ROW_STEP

    // Wave butterfly reduction (one-time), then lane 0 atomics 20 partials.
#pragma unroll
    for (int s = 0; s < NS; ++s) {
#pragma unroll
        for (int c = 0; c < 2; ++c) {
            float v = acc[s][c];
#pragma unroll
            for (int off = 32; off > 0; off >>= 1) v += __shfl_xor(v, off);
            if (lane == 0) atomicAdd(&out[((size_t)b * DCH + ch + c) * NS + s], v);
        }
    }
}

extern "C" void kernel_launch(void* const* d_in, const int* in_sizes, int n_in,
                              void* d_out, int out_size, void* d_ws, size_t ws_size,
                              hipStream_t stream) {
    const float* x = (const float*)d_in[0];
    float* out = (float*)d_out;
    const int nblk = (out_size + 255) / 256;
    zero_kernel<<<nblk, 256, 0, stream>>>(out, out_size);
    pool_kernel<<<NBLK, 256, 0, stream>>>(x, out);
    finalize_kernel<<<nblk, 256, 0, stream>>>(out, out_size);
}